// Round 1
// baseline (361.303 us; speedup 1.0000x reference)
//
#include <hip/hip_runtime.h>

// Problem constants (B=1)
constexpr int NRES = 2048;   // N
constexpr int NBR  = 32;     // neighbors
constexpr int C    = 384;    // input channels
constexpr int C1   = 32;     // projected channels
constexpr int OUTD = 128;    // output channels
constexpr int SJ_LD = C + 4; // padded LDS leading dim: k-stride 388 % 32 == 4 -> 8 distinct banks

__global__ __launch_bounds__(256) void outerprod_kernel(
    const float* __restrict__ s_i, const float* __restrict__ s_j,
    const float* __restrict__ m_i, const float* __restrict__ m_j,
    const float* __restrict__ Wl,  const float* __restrict__ bl,
    const float* __restrict__ Wr,  const float* __restrict__ br,
    const float* __restrict__ Wo,  const float* __restrict__ bo,
    float* __restrict__ out)
{
    const int i = blockIdx.x;
    const int t = threadIdx.x;

    __shared__ float sA[C];               // s_i row
    __shared__ float lft[C1];             // left[i,:]
    __shared__ float sj[NBR * SJ_LD];     // s_j tile, padded rows (~48.5 KB)
    __shared__ float rgt[NBR * C1];       // right[i,:,:] (4 KB)
    __shared__ float Tm[C1 * OUTD];       // T_i (16 KB)

    // ---- load s_i row (coalesced) ----
    for (int c = t; c < C; c += 256) sA[c] = s_i[(size_t)i * C + c];
    __syncthreads();

    // ---- left projection: 32 threads, thread a computes left[a] ----
    if (t < C1) {
        float acc = bl[t];
        for (int c = 0; c < C; ++c)
            acc = fmaf(sA[c], Wl[c * C1 + t], acc);   // Wl coalesced across lanes
        lft[t] = m_i[i] * acc;
    }

    // ---- stage s_j tile into padded LDS (independent of left) ----
    {
        const float* src = s_j + (size_t)i * NBR * C;
        for (int e = t; e < NBR * C; e += 256) {
            int k = e / C, c = e - k * C;
            sj[k * SJ_LD + c] = src[e];
        }
    }
    __syncthreads();

    // ---- T[c][o] = sum_a lft[a] * Wo[(a*C1+c)*OUTD + o]  (16 elems/thread) ----
    for (int e = t; e < C1 * OUTD; e += 256) {
        const int c = e >> 7, o = e & (OUTD - 1);
        float acc = 0.f;
        #pragma unroll
        for (int a = 0; a < C1; ++a)
            acc = fmaf(lft[a], Wo[(a * C1 + c) * OUTD + o], acc);  // coalesced over e
        Tm[e] = acc;
    }

    // ---- right projection: one task/thread: k = t>>3, 4 consecutive c ----
    {
        const int k = t >> 3, cg = t & 7;
        float a0 = 0.f, a1 = 0.f, a2 = 0.f, a3 = 0.f;
        const float* wr = Wr + cg * 4;
        const float* sr = sj + k * SJ_LD;
        for (int cc = 0; cc < C; ++cc) {
            const float s = sr[cc];                                   // LDS broadcast, banks spread by pad
            const float4 w = *reinterpret_cast<const float4*>(wr + cc * C1); // one 128B line / wave / cc
            a0 = fmaf(s, w.x, a0);
            a1 = fmaf(s, w.y, a1);
            a2 = fmaf(s, w.z, a2);
            a3 = fmaf(s, w.w, a3);
        }
        const float  m  = m_j[i * NBR + k];
        const float4 b4 = *reinterpret_cast<const float4*>(br + cg * 4);
        rgt[k * C1 + cg * 4 + 0] = m * (a0 + b4.x);
        rgt[k * C1 + cg * 4 + 1] = m * (a1 + b4.y);
        rgt[k * C1 + cg * 4 + 2] = m * (a2 + b4.z);
        rgt[k * C1 + cg * 4 + 3] = m * (a3 + b4.w);
    }
    __syncthreads();

    // ---- out[i,k,o] = sum_c rgt[k,c] * T[c,o] + bo[o]  (4 float4 tasks/thread) ----
    for (int e = t; e < NBR * (OUTD / 4); e += 256) {
        const int k = e >> 5;
        const int o = (e & 31) * 4;
        const float4 b4 = *reinterpret_cast<const float4*>(bo + o);
        float a0 = b4.x, a1 = b4.y, a2 = b4.z, a3 = b4.w;
        #pragma unroll 8
        for (int c = 0; c < C1; ++c) {
            const float  r  = rgt[k * C1 + c];                        // broadcast (2 addrs/wave, free)
            const float4 tv = *reinterpret_cast<const float4*>(&Tm[c * OUTD + o]); // b128, conflict-free
            a0 = fmaf(r, tv.x, a0);
            a1 = fmaf(r, tv.y, a1);
            a2 = fmaf(r, tv.z, a2);
            a3 = fmaf(r, tv.w, a3);
        }
        const float4 res = {a0, a1, a2, a3};
        *reinterpret_cast<float4*>(&out[((size_t)i * NBR + k) * OUTD + o]) = res;
    }
}

extern "C" void kernel_launch(void* const* d_in, const int* in_sizes, int n_in,
                              void* d_out, int out_size, void* d_ws, size_t ws_size,
                              hipStream_t stream) {
    (void)in_sizes; (void)n_in; (void)out_size; (void)d_ws; (void)ws_size;
    const float* s_i = (const float*)d_in[0];
    const float* s_j = (const float*)d_in[1];
    const float* m_i = (const float*)d_in[2];
    const float* m_j = (const float*)d_in[3];
    const float* Wl  = (const float*)d_in[4];
    const float* bl  = (const float*)d_in[5];
    const float* Wr  = (const float*)d_in[6];
    const float* br  = (const float*)d_in[7];
    const float* Wo  = (const float*)d_in[8];
    const float* bo  = (const float*)d_in[9];
    float* out = (float*)d_out;

    outerprod_kernel<<<NRES, 256, 0, stream>>>(
        s_i, s_j, m_i, m_j, Wl, bl, Wr, br, Wo, bo, out);
}

// Round 2
// 325.587 us; speedup vs baseline: 1.1097x; 1.1097x over previous
//
#include <hip/hip_runtime.h>

// Problem constants (B=1)
constexpr int NRES = 2048;   // N
constexpr int NBR  = 32;     // neighbors
constexpr int C    = 384;    // input channels
constexpr int C1   = 32;     // projected channels
constexpr int OUTD = 128;    // output channels

__global__ __launch_bounds__(256, 6) void outerprod_kernel(
    const float* __restrict__ s_i, const float* __restrict__ s_j,
    const float* __restrict__ m_i, const float* __restrict__ m_j,
    const float* __restrict__ Wl,  const float* __restrict__ bl,
    const float* __restrict__ Wr,  const float* __restrict__ br,
    const float* __restrict__ Wo,  const float* __restrict__ bo,
    float* __restrict__ out)
{
    const int i = blockIdx.x;
    const int t = threadIdx.x;

    __shared__ float red[8][C1];      // left partials (1 KB)
    __shared__ float lft[C1];         // left[i,:] (128 B)
    __shared__ float rgt[NBR * C1];   // right[i,:,:] (4 KB)
    __shared__ float Tm[C1 * OUTD];   // T_i[c][o] (16 KB)
    // total ~21.6 KB -> 7 blocks/CU

    // ---- Phase 1: left partials, all 256 threads ----
    // t = a + 32*g : group g sums c in [g*48, g*48+48)
    {
        const int a = t & 31, g = t >> 5;
        const float* si = s_i + (size_t)i * C;
        const int c0 = g * 48;
        float acc = 0.f;
        #pragma unroll 4
        for (int c = c0; c < c0 + 48; c += 4) {
            const float4 s4 = *reinterpret_cast<const float4*>(si + c); // broadcast in 32-lane group
            acc = fmaf(s4.x, Wl[(c + 0) * C1 + a], acc);   // Wl coalesced across lanes
            acc = fmaf(s4.y, Wl[(c + 1) * C1 + a], acc);
            acc = fmaf(s4.z, Wl[(c + 2) * C1 + a], acc);
            acc = fmaf(s4.w, Wl[(c + 3) * C1 + a], acc);
        }
        red[g][a] = acc;
    }
    __syncthreads();

    // ---- Phase 2a: reduce left (threads 0..31), others fall through ----
    if (t < C1) {
        float acc = bl[t];
        #pragma unroll
        for (int g = 0; g < 8; ++g) acc += red[g][t];
        lft[t] = m_i[i] * acc;
    }

    // ---- Phase 2b: right projection (all threads, independent of left) ----
    // thread: k = t>>3, cg = t&7 -> output channels c = cg*4 .. cg*4+3
    {
        const int k = t >> 3, cg = t & 7;
        const float* sr = s_j + ((size_t)i * NBR + k) * C;
        const float* wr = Wr + cg * 4;
        float a0 = 0.f, a1 = 0.f, a2 = 0.f, a3 = 0.f;
        #pragma unroll 4
        for (int cc = 0; cc < C; cc += 4) {
            const float4 s4 = *reinterpret_cast<const float4*>(sr + cc); // 8-way broadcast via L1
            float4 w;
            w = *reinterpret_cast<const float4*>(wr + (cc + 0) * C1);    // one 128B line/wave/cc
            a0 = fmaf(s4.x, w.x, a0); a1 = fmaf(s4.x, w.y, a1);
            a2 = fmaf(s4.x, w.z, a2); a3 = fmaf(s4.x, w.w, a3);
            w = *reinterpret_cast<const float4*>(wr + (cc + 1) * C1);
            a0 = fmaf(s4.y, w.x, a0); a1 = fmaf(s4.y, w.y, a1);
            a2 = fmaf(s4.y, w.z, a2); a3 = fmaf(s4.y, w.w, a3);
            w = *reinterpret_cast<const float4*>(wr + (cc + 2) * C1);
            a0 = fmaf(s4.z, w.x, a0); a1 = fmaf(s4.z, w.y, a1);
            a2 = fmaf(s4.z, w.z, a2); a3 = fmaf(s4.z, w.w, a3);
            w = *reinterpret_cast<const float4*>(wr + (cc + 3) * C1);
            a0 = fmaf(s4.w, w.x, a0); a1 = fmaf(s4.w, w.y, a1);
            a2 = fmaf(s4.w, w.z, a2); a3 = fmaf(s4.w, w.w, a3);
        }
        const float  m  = m_j[i * NBR + k];
        const float4 b4 = *reinterpret_cast<const float4*>(br + cg * 4);
        rgt[k * C1 + cg * 4 + 0] = m * (a0 + b4.x);
        rgt[k * C1 + cg * 4 + 1] = m * (a1 + b4.y);
        rgt[k * C1 + cg * 4 + 2] = m * (a2 + b4.z);
        rgt[k * C1 + cg * 4 + 3] = m * (a3 + b4.w);
    }
    __syncthreads();

    // ---- Phase 3: T[c][o] = sum_a lft[a] * Wo[(a*C1+c)*OUTD+o], float4 per task ----
    // 1024 float4 tasks / 256 threads = 4 tasks/thread
    #pragma unroll
    for (int j = 0; j < 4; ++j) {
        const int e4 = t + j * 256;
        const int c  = e4 >> 5;            // uniform per 32-lane group
        const int o  = (e4 & 31) * 4;      // coalesced across lanes
        float a0 = 0.f, a1 = 0.f, a2 = 0.f, a3 = 0.f;
        #pragma unroll 8
        for (int a = 0; a < C1; ++a) {
            const float  l  = lft[a];      // LDS broadcast
            const float4 w4 = *reinterpret_cast<const float4*>(
                Wo + ((size_t)(a * C1 + c)) * OUTD + o);
            a0 = fmaf(l, w4.x, a0); a1 = fmaf(l, w4.y, a1);
            a2 = fmaf(l, w4.z, a2); a3 = fmaf(l, w4.w, a3);
        }
        float4 r = {a0, a1, a2, a3};
        *reinterpret_cast<float4*>(&Tm[c * OUTD + o]) = r;
    }
    __syncthreads();

    // ---- Phase 4: out[i,k,o] = sum_c rgt[k,c]*T[c,o] + bo[o] ----
    #pragma unroll
    for (int j = 0; j < 4; ++j) {
        const int e4 = t + j * 256;
        const int k  = e4 >> 5;
        const int o  = (e4 & 31) * 4;
        const float4 b4 = *reinterpret_cast<const float4*>(bo + o);
        float a0 = b4.x, a1 = b4.y, a2 = b4.z, a3 = b4.w;
        #pragma unroll 8
        for (int c = 0; c < C1; ++c) {
            const float  r  = rgt[k * C1 + c];   // broadcast per 32-lane group
            const float4 tv = *reinterpret_cast<const float4*>(&Tm[c * OUTD + o]);
            a0 = fmaf(r, tv.x, a0); a1 = fmaf(r, tv.y, a1);
            a2 = fmaf(r, tv.z, a2); a3 = fmaf(r, tv.w, a3);
        }
        const float4 res = {a0, a1, a2, a3};
        *reinterpret_cast<float4*>(&out[((size_t)i * NBR + k) * OUTD + o]) = res;
    }
}

extern "C" void kernel_launch(void* const* d_in, const int* in_sizes, int n_in,
                              void* d_out, int out_size, void* d_ws, size_t ws_size,
                              hipStream_t stream) {
    (void)in_sizes; (void)n_in; (void)out_size; (void)d_ws; (void)ws_size;
    const float* s_i = (const float*)d_in[0];
    const float* s_j = (const float*)d_in[1];
    const float* m_i = (const float*)d_in[2];
    const float* m_j = (const float*)d_in[3];
    const float* Wl  = (const float*)d_in[4];
    const float* bl  = (const float*)d_in[5];
    const float* Wr  = (const float*)d_in[6];
    const float* br  = (const float*)d_in[7];
    const float* Wo  = (const float*)d_in[8];
    const float* bo  = (const float*)d_in[9];
    float* out = (float*)d_out;

    outerprod_kernel<<<NRES, 256, 0, stream>>>(
        s_i, s_j, m_i, m_j, Wl, bl, Wr, br, Wo, bo, out);
}

// Round 3
// 317.878 us; speedup vs baseline: 1.1366x; 1.0242x over previous
//
#include <hip/hip_runtime.h>

// Problem constants (B=1)
constexpr int NRES = 2048;   // N
constexpr int NBR  = 32;     // neighbors
constexpr int C    = 384;    // input channels
constexpr int C1   = 32;     // projected channels
constexpr int OUTD = 128;    // output channels

constexpr int CHUNK = 64;            // s_j channels per staged chunk
constexpr int NCH   = C / CHUNK;     // 6 chunks
constexpr int SJ_LD = CHUNK + 4;     // 68: k-stride 68 % 32 = 4 -> 8 distinct bank groups

__global__ __launch_bounds__(256, 4) void outerprod_kernel(
    const float* __restrict__ s_i, const float* __restrict__ s_j,
    const float* __restrict__ m_i, const float* __restrict__ m_j,
    const float* __restrict__ Wl,  const float* __restrict__ bl,
    const float* __restrict__ Wr,  const float* __restrict__ br,
    const float* __restrict__ Wo,  const float* __restrict__ bo,
    float* __restrict__ out)
{
    const int i = blockIdx.x;
    const int t = threadIdx.x;

    __shared__ float red[8][C1];            // left partials (1 KB)
    __shared__ float lft[C1];               // left[i,:]
    __shared__ float rgt[NBR * C1];         // right[i,:,:] (4 KB)
    __shared__ float Tm[C1 * OUTD];         // T_i[c][o] (16 KB)
    __shared__ float sj[2][NBR * SJ_LD];    // double-buffered s_j chunks (2 x 8.5 KB)
    // total ~39 KB -> 4 blocks/CU (16 waves)

    // staging map: float4 index f (0..511): row kk = f>>4, col4 = (f&15)*4
    const int f0 = t,        kk0 = f0 >> 4, c40 = (f0 & 15) * 4;
    const int f1 = t + 256,  kk1 = f1 >> 4, c41 = (f1 & 15) * 4;
    const float* sjbase = s_j + (size_t)i * NBR * C;

    // ---- prologue: issue chunk-0 global loads ----
    float4 st0 = *reinterpret_cast<const float4*>(sjbase + kk0 * C + c40);
    float4 st1 = *reinterpret_cast<const float4*>(sjbase + kk1 * C + c41);

    // ---- phase 1: left partials, all 256 threads ----
    {
        const int a = t & 31, g = t >> 5;
        const float* si = s_i + (size_t)i * C;
        const int c0 = g * 48;
        float acc = 0.f;
        #pragma unroll 4
        for (int c = c0; c < c0 + 48; c += 4) {
            const float4 s4 = *reinterpret_cast<const float4*>(si + c);
            acc = fmaf(s4.x, Wl[(c + 0) * C1 + a], acc);
            acc = fmaf(s4.y, Wl[(c + 1) * C1 + a], acc);
            acc = fmaf(s4.z, Wl[(c + 2) * C1 + a], acc);
            acc = fmaf(s4.w, Wl[(c + 3) * C1 + a], acc);
        }
        red[g][a] = acc;
    }
    __syncthreads();

    // write chunk 0 into sj[0]
    *reinterpret_cast<float4*>(&sj[0][kk0 * SJ_LD + c40]) = st0;
    *reinterpret_cast<float4*>(&sj[0][kk1 * SJ_LD + c41]) = st1;

    // left reduction (threads 0..31), overlaps with others' ds_writes
    if (t < C1) {
        float acc = bl[t];
        #pragma unroll
        for (int g = 0; g < 8; ++g) acc += red[g][t];
        lft[t] = m_i[i] * acc;
    }

    // ---- phase 2: right projection, double-buffered chunks ----
    const int k = t >> 3, cg = t & 7;
    float acc0 = 0.f, acc1 = 0.f, acc2 = 0.f, acc3 = 0.f;
    int cur = 0;
    for (int ch = 0; ch < NCH; ++ch) {
        // issue next chunk's global loads (latency hides under compute)
        if (ch + 1 < NCH) {
            st0 = *reinterpret_cast<const float4*>(sjbase + kk0 * C + (ch + 1) * CHUNK + c40);
            st1 = *reinterpret_cast<const float4*>(sjbase + kk1 * C + (ch + 1) * CHUNK + c41);
        }
        __syncthreads();   // sj[cur] fully written; prior reads of sj[cur^1] retired

        const float* srow  = &sj[cur][k * SJ_LD];
        const float* wbase = Wr + (size_t)(ch * CHUNK) * C1 + cg * 4;  // 8 KB slice: L1-resident
        #pragma unroll
        for (int c4 = 0; c4 < CHUNK / 4; ++c4) {
            const float4 s4 = *reinterpret_cast<const float4*>(srow + c4 * 4); // conflict-free b128
            float4 w;
            w = *reinterpret_cast<const float4*>(wbase + (c4 * 4 + 0) * C1);
            acc0 = fmaf(s4.x, w.x, acc0); acc1 = fmaf(s4.x, w.y, acc1);
            acc2 = fmaf(s4.x, w.z, acc2); acc3 = fmaf(s4.x, w.w, acc3);
            w = *reinterpret_cast<const float4*>(wbase + (c4 * 4 + 1) * C1);
            acc0 = fmaf(s4.y, w.x, acc0); acc1 = fmaf(s4.y, w.y, acc1);
            acc2 = fmaf(s4.y, w.z, acc2); acc3 = fmaf(s4.y, w.w, acc3);
            w = *reinterpret_cast<const float4*>(wbase + (c4 * 4 + 2) * C1);
            acc0 = fmaf(s4.z, w.x, acc0); acc1 = fmaf(s4.z, w.y, acc1);
            acc2 = fmaf(s4.z, w.z, acc2); acc3 = fmaf(s4.z, w.w, acc3);
            w = *reinterpret_cast<const float4*>(wbase + (c4 * 4 + 3) * C1);
            acc0 = fmaf(s4.w, w.x, acc0); acc1 = fmaf(s4.w, w.y, acc1);
            acc2 = fmaf(s4.w, w.z, acc2); acc3 = fmaf(s4.w, w.w, acc3);
        }

        if (ch + 1 < NCH) {
            *reinterpret_cast<float4*>(&sj[cur ^ 1][kk0 * SJ_LD + c40]) = st0;
            *reinterpret_cast<float4*>(&sj[cur ^ 1][kk1 * SJ_LD + c41]) = st1;
        }
        cur ^= 1;
    }
    {
        const float  m  = m_j[i * NBR + k];
        const float4 b4 = *reinterpret_cast<const float4*>(br + cg * 4);
        rgt[k * C1 + cg * 4 + 0] = m * (acc0 + b4.x);
        rgt[k * C1 + cg * 4 + 1] = m * (acc1 + b4.y);
        rgt[k * C1 + cg * 4 + 2] = m * (acc2 + b4.z);
        rgt[k * C1 + cg * 4 + 3] = m * (acc3 + b4.w);
    }
    __syncthreads();   // rgt + lft ready

    // ---- phase 3: T[c][o] = sum_a lft[a] * Wo[(a*C1+c)*OUTD+o] ----
    #pragma unroll
    for (int j = 0; j < 4; ++j) {
        const int e4 = t + j * 256;
        const int c  = e4 >> 5;
        const int o  = (e4 & 31) * 4;
        float a0 = 0.f, a1 = 0.f, a2 = 0.f, a3 = 0.f;
        #pragma unroll 8
        for (int a = 0; a < C1; ++a) {
            const float  l  = lft[a];
            const float4 w4 = *reinterpret_cast<const float4*>(
                Wo + ((size_t)(a * C1 + c)) * OUTD + o);
            a0 = fmaf(l, w4.x, a0); a1 = fmaf(l, w4.y, a1);
            a2 = fmaf(l, w4.z, a2); a3 = fmaf(l, w4.w, a3);
        }
        float4 r = {a0, a1, a2, a3};
        *reinterpret_cast<float4*>(&Tm[c * OUTD + o]) = r;
    }
    __syncthreads();

    // ---- phase 4: out[i,k,o] = sum_c rgt[k,c]*T[c,o] + bo[o] ----
    #pragma unroll
    for (int j = 0; j < 4; ++j) {
        const int e4 = t + j * 256;
        const int kk = e4 >> 5;
        const int o  = (e4 & 31) * 4;
        const float4 b4 = *reinterpret_cast<const float4*>(bo + o);
        float a0 = b4.x, a1 = b4.y, a2 = b4.z, a3 = b4.w;
        #pragma unroll 8
        for (int c = 0; c < C1; ++c) {
            const float  r  = rgt[kk * C1 + c];
            const float4 tv = *reinterpret_cast<const float4*>(&Tm[c * OUTD + o]);
            a0 = fmaf(r, tv.x, a0); a1 = fmaf(r, tv.y, a1);
            a2 = fmaf(r, tv.z, a2); a3 = fmaf(r, tv.w, a3);
        }
        const float4 res = {a0, a1, a2, a3};
        *reinterpret_cast<float4*>(&out[((size_t)i * NBR + kk) * OUTD + o]) = res;
    }
}

extern "C" void kernel_launch(void* const* d_in, const int* in_sizes, int n_in,
                              void* d_out, int out_size, void* d_ws, size_t ws_size,
                              hipStream_t stream) {
    (void)in_sizes; (void)n_in; (void)out_size; (void)d_ws; (void)ws_size;
    const float* s_i = (const float*)d_in[0];
    const float* s_j = (const float*)d_in[1];
    const float* m_i = (const float*)d_in[2];
    const float* m_j = (const float*)d_in[3];
    const float* Wl  = (const float*)d_in[4];
    const float* bl  = (const float*)d_in[5];
    const float* Wr  = (const float*)d_in[6];
    const float* br  = (const float*)d_in[7];
    const float* Wo  = (const float*)d_in[8];
    const float* bo  = (const float*)d_in[9];
    float* out = (float*)d_out;

    outerprod_kernel<<<NRES, 256, 0, stream>>>(
        s_i, s_j, m_i, m_j, Wl, bl, Wr, br, Wo, bo, out);
}

// Round 4
// 281.746 us; speedup vs baseline: 1.2824x; 1.1282x over previous
//
#include <hip/hip_runtime.h>

// Problem constants (B=1)
constexpr int NRES = 2048;   // N residues
constexpr int NBR  = 32;     // neighbors
constexpr int C    = 384;    // input channels
constexpr int C1   = 32;     // projected channels
constexpr int OUTD = 128;    // output channels
constexpr int M1   = NRES * NBR;   // 65536 flattened (i,k) rows

// workspace layout
constexpr size_t R_OFF = 0;                          // R^T [C1][M1] f32 : 8 MB
constexpr size_t L_OFF = (size_t)8 << 20;            // L [NRES][C1] f32 : 256 KB
constexpr size_t T_OFF = (size_t)9 << 20;            // T [NRES][4096] f32 : 32 MB
constexpr size_t WS_NEED = T_OFF + (size_t)NRES * (C1 * OUTD) * sizeof(float);

// ================= K1: R^T = (m_j (S_j@Wr + br))^T  and  L = m_i (S_i@Wl + bl) =========
// Grid 512 blocks x 256 thr. Block b owns rows [b*128, b*128+128) of (i,k) and 4 residues.
// Wave w computes its 128 rows x 8 n-cols with Wr via wave-uniform scalar loads.
__global__ __launch_bounds__(256) void k1_proj(
    const float* __restrict__ s_i, const float* __restrict__ s_j,
    const float* __restrict__ m_i, const float* __restrict__ m_j,
    const float* __restrict__ Wl,  const float* __restrict__ bl,
    const float* __restrict__ Wr,  const float* __restrict__ br,
    float* __restrict__ Rt, float* __restrict__ Lg)
{
    const int b    = blockIdx.x;
    const int t    = threadIdx.x;
    const int lane = t & 63;
    const int n0   = __builtin_amdgcn_readfirstlane((t >> 6) * 8);  // wave's n-base (SGPR)

    __shared__ float sj[128 * 32];   // one K-chunk, XOR-swizzled 16B slots (16 KB)

    // ---- prologue: stage chunk 0 into regs (latency hides under L-phase) ----
    float4 st[4];
    #pragma unroll
    for (int j = 0; j < 4; ++j) {
        const int idx = t + j * 256, r = idx >> 3, c4 = idx & 7;
        st[j] = *(const float4*)(s_j + (size_t)(b * 128 + r) * C + c4 * 4);
    }

    // ---- L-phase: threads 0..127 compute L for the block's 4 residues ----
    if (t < 128) {
        const int ii = t >> 5, a = t & 31;
        const int gi = b * 4 + ii;
        const float* si = s_i + (size_t)gi * C;
        float acc = bl[a];
        #pragma unroll 4
        for (int c = 0; c < C; c += 4) {
            const float4 s4 = *(const float4*)(si + c);       // broadcast per ii
            acc = fmaf(s4.x, Wl[(c + 0) * C1 + a], acc);      // coalesced over a
            acc = fmaf(s4.y, Wl[(c + 1) * C1 + a], acc);
            acc = fmaf(s4.z, Wl[(c + 2) * C1 + a], acc);
            acc = fmaf(s4.w, Wl[(c + 3) * C1 + a], acc);
        }
        Lg[gi * C1 + a] = m_i[gi] * acc;
    }

    // ---- main loop: 12 K-chunks of 32 ----
    float a0[8], a1[8];
    #pragma unroll
    for (int j = 0; j < 8; ++j) { a0[j] = 0.f; a1[j] = 0.f; }
    const int row0 = lane, row1 = lane + 64;
    const int sw0 = row0 & 7;           // row1&7 == row0&7 (64 = 0 mod 8)

    for (int ch = 0; ch < 12; ++ch) {
        // write staged chunk into LDS (slot XOR-swizzle: bank-conflict-free r/w)
        #pragma unroll
        for (int j = 0; j < 4; ++j) {
            const int idx = t + j * 256, r = idx >> 3, c4 = idx & 7;
            *(float4*)(&sj[r * 32 + ((c4 ^ (r & 7)) << 2)]) = st[j];
        }
        // prefetch next chunk to regs
        if (ch < 11) {
            #pragma unroll
            for (int j = 0; j < 4; ++j) {
                const int idx = t + j * 256, r = idx >> 3, c4 = idx & 7;
                st[j] = *(const float4*)(s_j + (size_t)(b * 128 + r) * C + (ch + 1) * 32 + c4 * 4);
            }
        }
        __syncthreads();   // LDS chunk visible

        #pragma unroll
        for (int k4 = 0; k4 < 8; ++k4) {
            const float4 sa0 = *(const float4*)(&sj[row0 * 32 + ((k4 ^ sw0) << 2)]);
            const float4 sa1 = *(const float4*)(&sj[row1 * 32 + ((k4 ^ sw0) << 2)]);
            const float s0v[4] = {sa0.x, sa0.y, sa0.z, sa0.w};
            const float s1v[4] = {sa1.x, sa1.y, sa1.z, sa1.w};
            #pragma unroll
            for (int q = 0; q < 4; ++q) {
                const int kk = ch * 32 + k4 * 4 + q;
                #pragma unroll
                for (int j = 0; j < 8; ++j) {
                    const float w = Wr[kk * C1 + n0 + j];   // wave-uniform -> s_load
                    a0[j] = fmaf(s0v[q], w, a0[j]);
                    a1[j] = fmaf(s1v[q], w, a1[j]);
                }
            }
        }
        __syncthreads();   // all reads done before next chunk's writes
    }

    // ---- epilogue: mask + bias, store R transposed [n][row] (coalesced over lanes) ----
    const int gr0 = b * 128 + row0, gr1 = b * 128 + row1;
    const float mj0 = m_j[gr0], mj1 = m_j[gr1];
    #pragma unroll
    for (int j = 0; j < 8; ++j) {
        const float rb = br[n0 + j];                        // uniform -> s_load
        Rt[(size_t)(n0 + j) * M1 + gr0] = mj0 * (a0[j] + rb);
        Rt[(size_t)(n0 + j) * M1 + gr1] = mj1 * (a1[j] + rb);
    }
}

// ================= K2: T[i][n] = sum_a L[i][a] * Wo[a*4096 + n]  (n = c*128+o) =========
// Grid 256 blocks (32 i-blocks x 8 n-blocks), 256 thr. Wave owns 16 i x 512 n.
__global__ __launch_bounds__(256) void k2_T(
    const float* __restrict__ Lg, const float* __restrict__ Wo,
    float* __restrict__ T)
{
    const int bi = blockIdx.x >> 3, bn = blockIdx.x & 7;
    const int t = threadIdx.x, lane = t & 63;
    const int ibase = __builtin_amdgcn_readfirstlane(bi * 64 + (t >> 6) * 16); // SGPR
    const int nlo = bn * 512 + lane * 4;
    const int nhi = nlo + 256;

    float4 accL[16], accH[16];
    #pragma unroll
    for (int ii = 0; ii < 16; ++ii) {
        accL[ii] = {0.f, 0.f, 0.f, 0.f};
        accH[ii] = {0.f, 0.f, 0.f, 0.f};
    }

    #pragma unroll 1
    for (int a4 = 0; a4 < 8; ++a4) {
        #pragma unroll
        for (int q = 0; q < 4; ++q) {
            const int a = a4 * 4 + q;
            const float4 w0 = *(const float4*)(Wo + (size_t)a * 4096 + nlo); // coalesced
            const float4 w1 = *(const float4*)(Wo + (size_t)a * 4096 + nhi);
            #pragma unroll
            for (int ii = 0; ii < 16; ++ii) {
                const float lv = Lg[(ibase + ii) * C1 + a];  // uniform -> s_load
                accL[ii].x = fmaf(lv, w0.x, accL[ii].x);
                accL[ii].y = fmaf(lv, w0.y, accL[ii].y);
                accL[ii].z = fmaf(lv, w0.z, accL[ii].z);
                accL[ii].w = fmaf(lv, w0.w, accL[ii].w);
                accH[ii].x = fmaf(lv, w1.x, accH[ii].x);
                accH[ii].y = fmaf(lv, w1.y, accH[ii].y);
                accH[ii].z = fmaf(lv, w1.z, accH[ii].z);
                accH[ii].w = fmaf(lv, w1.w, accH[ii].w);
            }
        }
    }
    #pragma unroll
    for (int ii = 0; ii < 16; ++ii) {
        *(float4*)(T + (size_t)(ibase + ii) * 4096 + nlo) = accL[ii];
        *(float4*)(T + (size_t)(ibase + ii) * 4096 + nhi) = accH[ii];
    }
}

// ================= K3: out[i,k,o] = sum_c R[i,k,c] * T[i][c*128+o] + bo[o] =============
// Grid 2048 blocks (one residue each), 256 thr. Wave owns 8 k x 128 o; lane owns 2 o.
__global__ __launch_bounds__(256) void k3_out(
    const float* __restrict__ Rt, const float* __restrict__ T,
    const float* __restrict__ bo, float* __restrict__ out)
{
    const int i = blockIdx.x;
    const int t = threadIdx.x, lane = t & 63;
    const int k0 = __builtin_amdgcn_readfirstlane((t >> 6) * 8);  // SGPR
    const int o  = lane * 2;
    const float* Trow = T + (size_t)i * 4096;

    float accx[8], accy[8];
    #pragma unroll
    for (int r = 0; r < 8; ++r) { accx[r] = 0.f; accy[r] = 0.f; }

    #pragma unroll 4
    for (int c = 0; c < C1; ++c) {
        const float2 tv = *(const float2*)(Trow + c * OUTD + o);   // coalesced stream
        #pragma unroll
        for (int r = 0; r < 8; ++r) {
            const float rv = Rt[(size_t)c * M1 + i * NBR + k0 + r]; // uniform -> s_load
            accx[r] = fmaf(rv, tv.x, accx[r]);
            accy[r] = fmaf(rv, tv.y, accy[r]);
        }
    }
    const float2 b2 = *(const float2*)(bo + o);
    #pragma unroll
    for (int r = 0; r < 8; ++r) {
        const float2 res = {accx[r] + b2.x, accy[r] + b2.y};
        *(float2*)(out + ((size_t)i * NBR + k0 + r) * OUTD + o) = res;
    }
}

// ================= Fallback (R3 fused kernel) if workspace is too small ================
constexpr int FCHUNK = 64, FNCH = C / FCHUNK, FSJ_LD = FCHUNK + 4;

__global__ __launch_bounds__(256, 4) void outerprod_fallback(
    const float* __restrict__ s_i, const float* __restrict__ s_j,
    const float* __restrict__ m_i, const float* __restrict__ m_j,
    const float* __restrict__ Wl,  const float* __restrict__ bl,
    const float* __restrict__ Wr,  const float* __restrict__ br,
    const float* __restrict__ Wo,  const float* __restrict__ bo,
    float* __restrict__ out)
{
    const int i = blockIdx.x;
    const int t = threadIdx.x;
    __shared__ float red[8][C1];
    __shared__ float lft[C1];
    __shared__ float rgt[NBR * C1];
    __shared__ float Tm[C1 * OUTD];
    __shared__ float sj[2][NBR * FSJ_LD];

    const int f0 = t,       kk0 = f0 >> 4, c40 = (f0 & 15) * 4;
    const int f1 = t + 256, kk1 = f1 >> 4, c41 = (f1 & 15) * 4;
    const float* sjbase = s_j + (size_t)i * NBR * C;
    float4 st0 = *(const float4*)(sjbase + kk0 * C + c40);
    float4 st1 = *(const float4*)(sjbase + kk1 * C + c41);
    {
        const int a = t & 31, g = t >> 5;
        const float* si = s_i + (size_t)i * C;
        const int c0 = g * 48;
        float acc = 0.f;
        #pragma unroll 4
        for (int c = c0; c < c0 + 48; c += 4) {
            const float4 s4 = *(const float4*)(si + c);
            acc = fmaf(s4.x, Wl[(c + 0) * C1 + a], acc);
            acc = fmaf(s4.y, Wl[(c + 1) * C1 + a], acc);
            acc = fmaf(s4.z, Wl[(c + 2) * C1 + a], acc);
            acc = fmaf(s4.w, Wl[(c + 3) * C1 + a], acc);
        }
        red[g][a] = acc;
    }
    __syncthreads();
    *(float4*)(&sj[0][kk0 * FSJ_LD + c40]) = st0;
    *(float4*)(&sj[0][kk1 * FSJ_LD + c41]) = st1;
    if (t < C1) {
        float acc = bl[t];
        #pragma unroll
        for (int g = 0; g < 8; ++g) acc += red[g][t];
        lft[t] = m_i[i] * acc;
    }
    const int k = t >> 3, cg = t & 7;
    float acc0 = 0.f, acc1 = 0.f, acc2 = 0.f, acc3 = 0.f;
    int cur = 0;
    for (int ch = 0; ch < FNCH; ++ch) {
        if (ch + 1 < FNCH) {
            st0 = *(const float4*)(sjbase + kk0 * C + (ch + 1) * FCHUNK + c40);
            st1 = *(const float4*)(sjbase + kk1 * C + (ch + 1) * FCHUNK + c41);
        }
        __syncthreads();
        const float* srow  = &sj[cur][k * FSJ_LD];
        const float* wbase = Wr + (size_t)(ch * FCHUNK) * C1 + cg * 4;
        #pragma unroll
        for (int c4 = 0; c4 < FCHUNK / 4; ++c4) {
            const float4 s4 = *(const float4*)(srow + c4 * 4);
            float4 w;
            w = *(const float4*)(wbase + (c4 * 4 + 0) * C1);
            acc0 = fmaf(s4.x, w.x, acc0); acc1 = fmaf(s4.x, w.y, acc1);
            acc2 = fmaf(s4.x, w.z, acc2); acc3 = fmaf(s4.x, w.w, acc3);
            w = *(const float4*)(wbase + (c4 * 4 + 1) * C1);
            acc0 = fmaf(s4.y, w.x, acc0); acc1 = fmaf(s4.y, w.y, acc1);
            acc2 = fmaf(s4.y, w.z, acc2); acc3 = fmaf(s4.y, w.w, acc3);
            w = *(const float4*)(wbase + (c4 * 4 + 2) * C1);
            acc0 = fmaf(s4.z, w.x, acc0); acc1 = fmaf(s4.z, w.y, acc1);
            acc2 = fmaf(s4.z, w.z, acc2); acc3 = fmaf(s4.z, w.w, acc3);
            w = *(const float4*)(wbase + (c4 * 4 + 3) * C1);
            acc0 = fmaf(s4.w, w.x, acc0); acc1 = fmaf(s4.w, w.y, acc1);
            acc2 = fmaf(s4.w, w.z, acc2); acc3 = fmaf(s4.w, w.w, acc3);
        }
        if (ch + 1 < FNCH) {
            *(float4*)(&sj[cur ^ 1][kk0 * FSJ_LD + c40]) = st0;
            *(float4*)(&sj[cur ^ 1][kk1 * FSJ_LD + c41]) = st1;
        }
        cur ^= 1;
    }
    {
        const float  m  = m_j[i * NBR + k];
        const float4 b4 = *(const float4*)(br + cg * 4);
        rgt[k * C1 + cg * 4 + 0] = m * (acc0 + b4.x);
        rgt[k * C1 + cg * 4 + 1] = m * (acc1 + b4.y);
        rgt[k * C1 + cg * 4 + 2] = m * (acc2 + b4.z);
        rgt[k * C1 + cg * 4 + 3] = m * (acc3 + b4.w);
    }
    __syncthreads();
    #pragma unroll
    for (int j = 0; j < 4; ++j) {
        const int e4 = t + j * 256;
        const int c  = e4 >> 5;
        const int o  = (e4 & 31) * 4;
        float x0 = 0.f, x1 = 0.f, x2 = 0.f, x3 = 0.f;
        #pragma unroll 8
        for (int a = 0; a < C1; ++a) {
            const float  l  = lft[a];
            const float4 w4 = *(const float4*)(Wo + ((size_t)(a * C1 + c)) * OUTD + o);
            x0 = fmaf(l, w4.x, x0); x1 = fmaf(l, w4.y, x1);
            x2 = fmaf(l, w4.z, x2); x3 = fmaf(l, w4.w, x3);
        }
        float4 r = {x0, x1, x2, x3};
        *(float4*)(&Tm[c * OUTD + o]) = r;
    }
    __syncthreads();
    #pragma unroll
    for (int j = 0; j < 4; ++j) {
        const int e4 = t + j * 256;
        const int kk = e4 >> 5;
        const int o  = (e4 & 31) * 4;
        const float4 b4 = *(const float4*)(bo + o);
        float x0 = b4.x, x1 = b4.y, x2 = b4.z, x3 = b4.w;
        #pragma unroll 8
        for (int c = 0; c < C1; ++c) {
            const float  r  = rgt[kk * C1 + c];
            const float4 tv = *(const float4*)(&Tm[c * OUTD + o]);
            x0 = fmaf(r, tv.x, x0); x1 = fmaf(r, tv.y, x1);
            x2 = fmaf(r, tv.z, x2); x3 = fmaf(r, tv.w, x3);
        }
        const float4 res = {x0, x1, x2, x3};
        *(float4*)(&out[((size_t)i * NBR + kk) * OUTD + o]) = res;
    }
}

extern "C" void kernel_launch(void* const* d_in, const int* in_sizes, int n_in,
                              void* d_out, int out_size, void* d_ws, size_t ws_size,
                              hipStream_t stream) {
    (void)in_sizes; (void)n_in; (void)out_size;
    const float* s_i = (const float*)d_in[0];
    const float* s_j = (const float*)d_in[1];
    const float* m_i = (const float*)d_in[2];
    const float* m_j = (const float*)d_in[3];
    const float* Wl  = (const float*)d_in[4];
    const float* bl  = (const float*)d_in[5];
    const float* Wr  = (const float*)d_in[6];
    const float* br  = (const float*)d_in[7];
    const float* Wo  = (const float*)d_in[8];
    const float* bo  = (const float*)d_in[9];
    float* out = (float*)d_out;

    if (ws_size >= WS_NEED) {
        float* Rt = (float*)((char*)d_ws + R_OFF);
        float* Lg = (float*)((char*)d_ws + L_OFF);
        float* T  = (float*)((char*)d_ws + T_OFF);
        k1_proj<<<M1 / 128, 256, 0, stream>>>(s_i, s_j, m_i, m_j, Wl, bl, Wr, br, Rt, Lg);
        k2_T<<<(NRES / 64) * 8, 256, 0, stream>>>(Lg, Wo, T);
        k3_out<<<NRES, 256, 0, stream>>>(Rt, T, bo, out);
    } else {
        outerprod_fallback<<<NRES, 256, 0, stream>>>(
            s_i, s_j, m_i, m_j, Wl, bl, Wr, br, Wo, bo, out);
    }
}